// Round 1
// baseline (369.710 us; speedup 1.0000x reference)
//
#include <hip/hip_runtime.h>
#include <hip/hip_bf16.h>
#include <math.h>

#define HIDDEN 256
#define NEG 1024
#define NBATCH 256
#define GAMMA_F 12.0f
#define BM 64
#define LDA 264   // A row stride in bf16 elems (+8 pad: banks 2-way, free)
#define LDB 40    // B row stride in bf16 elems (+8 pad)

typedef short v8s __attribute__((ext_vector_type(8)));
typedef float v4f __attribute__((ext_vector_type(4)));

// fp32 -> bf16 round-to-nearest-even (manual, no header dependency)
__device__ __forceinline__ short f2bf(float x) {
    unsigned int u = __float_as_uint(x);
    u = (u + 0x7fffu + ((u >> 16) & 1u)) >> 16;
    return (short)u;
}

// One block per batch row b: h_n[b,:], rel_part[b,:] in fp32; convert W1 row b -> bf16.
__global__ __launch_bounds__(256) void prep_kernel(
    const int* __restrict__ head, const int* __restrict__ relation,
    const float* __restrict__ entity_emb, const float* __restrict__ relation_emb,
    const float* __restrict__ W_fc, const float* __restrict__ b_fc,
    short* __restrict__ W1bf, float* __restrict__ h_n, float* __restrict__ rel_part)
{
    const int b = blockIdx.x;
    const int t = threadIdx.x;

    // W1 = W_fc[:, :256]; block b converts row b
    W1bf[b * HIDDEN + t] = f2bf(W_fc[(size_t)b * 2 * HIDDEN + t]);

    __shared__ float xh[2 * HIDDEN];   // h_cat = [h_emb | re_head]
    __shared__ float xt[HIDDEN];       // re_tail
    __shared__ float red[256];

    const int hidx = head[b];          // head is [B,1]
    const int r = relation[b];
    xh[t]          = entity_emb[(size_t)hidx * HIDDEN + t];
    xh[HIDDEN + t] = relation_emb[(size_t)r * 2 * HIDDEN + t];
    xt[t]          = relation_emb[(size_t)r * 2 * HIDDEN + HIDDEN + t];
    __syncthreads();

    const float4* wrow = reinterpret_cast<const float4*>(W_fc + (size_t)t * 2 * HIDDEN);
    float hf = b_fc[t];
    float rp = b_fc[t];
    #pragma unroll 4
    for (int kk = 0; kk < HIDDEN / 4; ++kk) {
        float4 w = wrow[kk];
        hf += xh[4*kk+0]*w.x + xh[4*kk+1]*w.y + xh[4*kk+2]*w.z + xh[4*kk+3]*w.w;
    }
    #pragma unroll 4
    for (int kk = 0; kk < HIDDEN / 4; ++kk) {
        float4 w = wrow[HIDDEN/4 + kk];
        hf += xh[HIDDEN+4*kk+0]*w.x + xh[HIDDEN+4*kk+1]*w.y + xh[HIDDEN+4*kk+2]*w.z + xh[HIDDEN+4*kk+3]*w.w;
        rp += xt[4*kk+0]*w.x + xt[4*kk+1]*w.y + xt[4*kk+2]*w.z + xt[4*kk+3]*w.w;
    }
    rel_part[b * HIDDEN + t] = rp;

    red[t] = hf * hf;
    __syncthreads();
    for (int s = 128; s > 0; s >>= 1) {
        if (t < s) red[t] += red[t + s];
        __syncthreads();
    }
    const float norm = sqrtf(red[0]);
    h_n[b * HIDDEN + t] = hf / fmaxf(norm, 1e-12f);
}

// Main: per block, 64 gathered tail rows x full 256 outputs, bf16 MFMA GEMM,
// then in-register normalize + L1 score epilogue (shfl butterflies, no LDS).
__global__ __launch_bounds__(256) void score_kernel(
    const int* __restrict__ tail, const float* __restrict__ entity_emb,
    const short* __restrict__ W1bf, const float* __restrict__ h_n,
    const float* __restrict__ rel_part, float* __restrict__ out)
{
    __shared__ __align__(16) short As[BM * LDA];       // 33792 B
    __shared__ __align__(16) short Bs[HIDDEN * LDB];   // 20480 B

    const int t = threadIdx.x;
    const int m0 = blockIdx.x * BM;      // 64 rows per block, all same b (64 | 1024)
    const int b = m0 >> 10;

    // ---- stage A: 64 gathered entity rows, f32 -> bf16 ----
    {
        const int rl = t >> 2;           // 0..63 local row
        const int q  = t & 3;            // quarter of the 256-wide row
        const int erow = tail[m0 + rl];
        const float4* s4 = reinterpret_cast<const float4*>(
            entity_emb + (size_t)erow * HIDDEN + q * 64);
        short* dst = As + rl * LDA + q * 64;
        #pragma unroll
        for (int it = 0; it < 8; ++it) {
            float4 a0 = s4[it*2], a1 = s4[it*2+1];
            v8s v;
            v[0]=f2bf(a0.x); v[1]=f2bf(a0.y); v[2]=f2bf(a0.z); v[3]=f2bf(a0.w);
            v[4]=f2bf(a1.x); v[5]=f2bf(a1.y); v[6]=f2bf(a1.z); v[7]=f2bf(a1.w);
            *reinterpret_cast<v8s*>(dst + it*8) = v;
        }
    }

    const int w    = t >> 6;   // wave 0..3 -> rows 16w..16w+15
    const int lane = t & 63;
    const int g    = lane >> 4;  // quad 0..3
    const int c    = lane & 15;

    v4f acc[16];
    #pragma unroll
    for (int i = 0; i < 16; ++i) acc[i] = v4f{0.f, 0.f, 0.f, 0.f};

    const short* a_base = As + (16 * w + c) * LDA + g * 8;  // A[m=lane&15][k=g*8+j]
    const short* b_base = Bs + c * LDB + g * 8;             // B[n=lane&15][k=g*8+j]

    for (int kt = 0; kt < 8; ++kt) {
        __syncthreads();
        {   // stage Bs = W1bf[:, kt*32 .. kt*32+31]
            const int chunk = t & 3;
            const int nrow  = t >> 2;
            const short* wsrc = W1bf + kt * 32 + chunk * 8;
            #pragma unroll
            for (int i = 0; i < 4; ++i) {
                const int n = nrow + 64 * i;
                v8s v = *reinterpret_cast<const v8s*>(wsrc + (size_t)n * HIDDEN);
                *reinterpret_cast<v8s*>(Bs + n * LDB + chunk * 8) = v;
            }
        }
        __syncthreads();
        v8s a = *reinterpret_cast<const v8s*>(a_base + kt * 32);
        #pragma unroll
        for (int nt = 0; nt < 16; ++nt) {
            v8s bf = *reinterpret_cast<const v8s*>(b_base + nt * 16 * LDB);
            acc[nt] = __builtin_amdgcn_mfma_f32_16x16x32_bf16(a, bf, acc[nt], 0, 0, 0);
        }
    }

    // ---- epilogue: t_fc = acc + rel_part[b]; normalize; score = GAMMA - ||h_n - t_n||_1
    // C/D layout: col d%16 = c (tile nt -> d = nt*16+c), row-in-tile = 4*g + reg.
    float hnv[16], rlv[16];
    #pragma unroll
    for (int nt = 0; nt < 16; ++nt) {
        const int d = nt * 16 + c;
        hnv[nt] = h_n[b * HIDDEN + d];
        rlv[nt] = rel_part[b * HIDDEN + d];
    }
    float sc4[4];
    #pragma unroll
    for (int reg = 0; reg < 4; ++reg) {
        float tf[16];
        float ssq = 0.f;
        #pragma unroll
        for (int nt = 0; nt < 16; ++nt) {
            tf[nt] = acc[nt][reg] + rlv[nt];
            ssq += tf[nt] * tf[nt];
        }
        #pragma unroll
        for (int mask = 1; mask < 16; mask <<= 1) ssq += __shfl_xor(ssq, mask);
        const float rn = 1.f / fmaxf(sqrtf(ssq), 1e-12f);
        float s = 0.f;
        #pragma unroll
        for (int nt = 0; nt < 16; ++nt) s += fabsf(hnv[nt] - tf[nt] * rn);
        #pragma unroll
        for (int mask = 1; mask < 16; mask <<= 1) s += __shfl_xor(s, mask);
        sc4[reg] = GAMMA_F - s;
    }
    if (c == 0) {
        float4 o = make_float4(sc4[0], sc4[1], sc4[2], sc4[3]);
        *reinterpret_cast<float4*>(out + m0 + 16 * w + 4 * g) = o;
    }
}

extern "C" void kernel_launch(void* const* d_in, const int* in_sizes, int n_in,
                              void* d_out, int out_size, void* d_ws, size_t ws_size,
                              hipStream_t stream)
{
    const int*   head         = (const int*)d_in[0];
    const int*   tail         = (const int*)d_in[1];
    const int*   relation     = (const int*)d_in[2];
    const float* entity_emb   = (const float*)d_in[3];
    const float* relation_emb = (const float*)d_in[4];
    const float* W_fc         = (const float*)d_in[5];
    const float* b_fc         = (const float*)d_in[6];
    float* out = (float*)d_out;

    // ws layout: W1 bf16 (128 KiB) | h_n f32 (256 KiB) | rel_part f32 (256 KiB)
    short* W1bf     = (short*)d_ws;
    float* h_n      = (float*)((char*)d_ws + 131072);
    float* rel_part = (float*)((char*)d_ws + 131072 + 262144);

    prep_kernel<<<NBATCH, 256, 0, stream>>>(head, relation, entity_emb, relation_emb,
                                            W_fc, b_fc, W1bf, h_n, rel_part);
    score_kernel<<<(NBATCH * NEG) / BM, 256, 0, stream>>>(tail, entity_emb, W1bf,
                                                          h_n, rel_part, out);
}

// Round 2
// 367.138 us; speedup vs baseline: 1.0070x; 1.0070x over previous
//
#include <hip/hip_runtime.h>
#include <math.h>

#define HIDDEN 256
#define NEG 1024
#define NBATCH 256
#define GAMMA_F 12.0f
#define BM 64

typedef short v8s __attribute__((ext_vector_type(8)));
typedef float v4f __attribute__((ext_vector_type(4)));

// fp32 -> bf16 round-to-nearest-even
__device__ __forceinline__ short f2bf(float x) {
    unsigned int u = __float_as_uint(x);
    u = (u + 0x7fffu + ((u >> 16) & 1u)) >> 16;
    return (short)u;
}

// One block per batch row b: h_n[b,:], rel_part[b,:] in fp32; convert W1 row b -> bf16.
__global__ __launch_bounds__(256) void prep_kernel(
    const int* __restrict__ head, const int* __restrict__ relation,
    const float* __restrict__ entity_emb, const float* __restrict__ relation_emb,
    const float* __restrict__ W_fc, const float* __restrict__ b_fc,
    short* __restrict__ W1bf, float* __restrict__ h_n, float* __restrict__ rel_part)
{
    const int b = blockIdx.x;
    const int t = threadIdx.x;

    W1bf[b * HIDDEN + t] = f2bf(W_fc[(size_t)b * 2 * HIDDEN + t]);

    __shared__ float xh[2 * HIDDEN];
    __shared__ float xt[HIDDEN];
    __shared__ float red[256];

    const int hidx = head[b];
    const int r = relation[b];
    xh[t]          = entity_emb[(size_t)hidx * HIDDEN + t];
    xh[HIDDEN + t] = relation_emb[(size_t)r * 2 * HIDDEN + t];
    xt[t]          = relation_emb[(size_t)r * 2 * HIDDEN + HIDDEN + t];
    __syncthreads();

    const float4* wrow = reinterpret_cast<const float4*>(W_fc + (size_t)t * 2 * HIDDEN);
    float hf = b_fc[t];
    float rp = b_fc[t];
    #pragma unroll 4
    for (int kk = 0; kk < HIDDEN / 4; ++kk) {
        float4 w = wrow[kk];
        hf += xh[4*kk+0]*w.x + xh[4*kk+1]*w.y + xh[4*kk+2]*w.z + xh[4*kk+3]*w.w;
    }
    #pragma unroll 4
    for (int kk = 0; kk < HIDDEN / 4; ++kk) {
        float4 w = wrow[HIDDEN/4 + kk];
        hf += xh[HIDDEN+4*kk+0]*w.x + xh[HIDDEN+4*kk+1]*w.y + xh[HIDDEN+4*kk+2]*w.z + xh[HIDDEN+4*kk+3]*w.w;
        rp += xt[4*kk+0]*w.x + xt[4*kk+1]*w.y + xt[4*kk+2]*w.z + xt[4*kk+3]*w.w;
    }
    rel_part[b * HIDDEN + t] = rp;

    red[t] = hf * hf;
    __syncthreads();
    for (int s = 128; s > 0; s >>= 1) {
        if (t < s) red[t] += red[t + s];
        __syncthreads();
    }
    const float norm = sqrtf(red[0]);
    h_n[b * HIDDEN + t] = hf / fmaxf(norm, 1e-12f);
}

// Main: 64 gathered rows x 256 cols per block. B-fragments live in registers
// (wave w owns cols 64w..64w+63); A tile in LDS in fragment-linear order so
// staging writes and K-loop reads are lane-linear (conflict-free).
// LDS unit (16B) index for (mt,kt,g,c): mt*512 + kt*64 + g*16 + c.
__global__ __launch_bounds__(256, 2) void score_kernel(
    const int* __restrict__ tail, const float* __restrict__ entity_emb,
    const short* __restrict__ W1bf, const float* __restrict__ h_n,
    const float* __restrict__ rel_part, float* __restrict__ out)
{
    __shared__ __align__(16) short As[BM * HIDDEN];   // 32 KiB, fragment-linear
    __shared__ float ssq_lds[4][BM];
    __shared__ float l1_lds[4][BM];

    const int t  = threadIdx.x;
    const int m0 = blockIdx.x * BM;
    const int b  = blockIdx.x >> 4;      // 1024/64 = 16 blocks per batch row

    const int c = t & 15;
    const int g = (t >> 4) & 3;
    const int w = t >> 6;
    const int l = t & 63;

    // tail indices for the 4 m-tiles this thread touches while staging
    int rows[4];
    #pragma unroll
    for (int mt = 0; mt < 4; ++mt) rows[mt] = tail[m0 + mt * 16 + c];

    // ---- stage A: global f32 -> bf16 -> LDS, lane-linear writes ----
    // unit L = t + 256*i decodes to c=L&15, g=(L>>4)&3, kt=(L>>6)&7, mt=L>>9
    #pragma unroll
    for (int i = 0; i < 8; ++i) {
        const int s  = w + 4 * i;        // 0..31
        const int kt = s & 7;
        const int mt = s >> 3;
        const float4* src = reinterpret_cast<const float4*>(
            entity_emb + (size_t)rows[mt] * HIDDEN + (kt * 4 + g) * 8);
        float4 a0 = src[0], a1 = src[1];
        v8s v;
        v[0]=f2bf(a0.x); v[1]=f2bf(a0.y); v[2]=f2bf(a0.z); v[3]=f2bf(a0.w);
        v[4]=f2bf(a1.x); v[5]=f2bf(a1.y); v[6]=f2bf(a1.z); v[7]=f2bf(a1.w);
        *reinterpret_cast<v8s*>(As + (t + 256 * i) * 8) = v;
    }

    // ---- preload all B fragments into registers (128 VGPRs) ----
    // B[n=lane&15][k=(lane>>4)*8+j] per 32-wide k-chunk; wave w: n += 64w
    v8s Bf[4][8];
    #pragma unroll
    for (int ntl = 0; ntl < 4; ++ntl) {
        const short* bsrc = W1bf + (size_t)(64 * w + ntl * 16 + c) * HIDDEN + g * 8;
        #pragma unroll
        for (int kt = 0; kt < 8; ++kt)
            Bf[ntl][kt] = *reinterpret_cast<const v8s*>(bsrc + kt * 32);
    }

    v4f acc[4][4];
    #pragma unroll
    for (int mt = 0; mt < 4; ++mt)
        #pragma unroll
        for (int ntl = 0; ntl < 4; ++ntl)
            acc[mt][ntl] = v4f{0.f, 0.f, 0.f, 0.f};

    __syncthreads();

    // ---- K-loop: no barriers, 4 ds_read_b128 + 16 MFMA per step ----
    #pragma unroll
    for (int kt = 0; kt < 8; ++kt) {
        v8s a[4];
        #pragma unroll
        for (int mt = 0; mt < 4; ++mt)
            a[mt] = *reinterpret_cast<const v8s*>(As + (mt * 512 + kt * 64 + l) * 8);
        #pragma unroll
        for (int mt = 0; mt < 4; ++mt) {
            #pragma unroll
            for (int ntl = 0; ntl < 4; ++ntl)
                acc[mt][ntl] = __builtin_amdgcn_mfma_f32_16x16x32_bf16(
                    a[mt], Bf[ntl][kt], acc[mt][ntl], 0, 0, 0);
        }
    }

    // ---- epilogue ----
    // C/D: tile (mt,ntl), lane (c,g), reg r -> row m=mt*16+g*4+r, col n=64w+ntl*16+c
    float rlv[4], hnv[4];
    #pragma unroll
    for (int ntl = 0; ntl < 4; ++ntl) {
        const int n = 64 * w + ntl * 16 + c;
        rlv[ntl] = rel_part[b * HIDDEN + n];
        hnv[ntl] = h_n[b * HIDDEN + n];
    }

    // phase 1: per-row partial sum of squares over this wave's 64 cols
    #pragma unroll
    for (int mt = 0; mt < 4; ++mt) {
        float ssq[4] = {0.f, 0.f, 0.f, 0.f};
        #pragma unroll
        for (int ntl = 0; ntl < 4; ++ntl) {
            #pragma unroll
            for (int r = 0; r < 4; ++r) {
                float tf = acc[mt][ntl][r] + rlv[ntl];
                acc[mt][ntl][r] = tf;
                ssq[r] += tf * tf;
            }
        }
        #pragma unroll
        for (int mask = 1; mask < 16; mask <<= 1) {
            #pragma unroll
            for (int r = 0; r < 4; ++r) ssq[r] += __shfl_xor(ssq[r], mask);
        }
        if (c == 0) {
            #pragma unroll
            for (int r = 0; r < 4; ++r) ssq_lds[w][mt * 16 + g * 4 + r] = ssq[r];
        }
    }
    __syncthreads();

    // phase 2: full norm per row, then partial L1 over this wave's cols
    #pragma unroll
    for (int mt = 0; mt < 4; ++mt) {
        float rn[4], s1[4] = {0.f, 0.f, 0.f, 0.f};
        #pragma unroll
        for (int r = 0; r < 4; ++r) {
            const int m = mt * 16 + g * 4 + r;
            float tot = ssq_lds[0][m] + ssq_lds[1][m] + ssq_lds[2][m] + ssq_lds[3][m];
            rn[r] = 1.f / fmaxf(sqrtf(tot), 1e-12f);
        }
        #pragma unroll
        for (int ntl = 0; ntl < 4; ++ntl) {
            #pragma unroll
            for (int r = 0; r < 4; ++r)
                s1[r] += fabsf(hnv[ntl] - acc[mt][ntl][r] * rn[r]);
        }
        #pragma unroll
        for (int mask = 1; mask < 16; mask <<= 1) {
            #pragma unroll
            for (int r = 0; r < 4; ++r) s1[r] += __shfl_xor(s1[r], mask);
        }
        if (c == 0) {
            #pragma unroll
            for (int r = 0; r < 4; ++r) l1_lds[w][mt * 16 + g * 4 + r] = s1[r];
        }
    }
    __syncthreads();

    if (t < BM) {
        out[m0 + t] = GAMMA_F -
            (l1_lds[0][t] + l1_lds[1][t] + l1_lds[2][t] + l1_lds[3][t]);
    }
}

extern "C" void kernel_launch(void* const* d_in, const int* in_sizes, int n_in,
                              void* d_out, int out_size, void* d_ws, size_t ws_size,
                              hipStream_t stream)
{
    const int*   head         = (const int*)d_in[0];
    const int*   tail         = (const int*)d_in[1];
    const int*   relation     = (const int*)d_in[2];
    const float* entity_emb   = (const float*)d_in[3];
    const float* relation_emb = (const float*)d_in[4];
    const float* W_fc         = (const float*)d_in[5];
    const float* b_fc         = (const float*)d_in[6];
    float* out = (float*)d_out;

    // ws layout: W1 bf16 (128 KiB) | h_n f32 (256 KiB) | rel_part f32 (256 KiB)
    short* W1bf     = (short*)d_ws;
    float* h_n      = (float*)((char*)d_ws + 131072);
    float* rel_part = (float*)((char*)d_ws + 131072 + 262144);

    prep_kernel<<<NBATCH, 256, 0, stream>>>(head, relation, entity_emb, relation_emb,
                                            W_fc, b_fc, W1bf, h_n, rel_part);
    score_kernel<<<(NBATCH * NEG) / BM, 256, 0, stream>>>(tail, entity_emb, W1bf,
                                                          h_n, rel_part, out);
}